// Round 1
// baseline (11406.811 us; speedup 1.0000x reference)
//
#include <hip/hip_runtime.h>

typedef __bf16 bf16x8 __attribute__((ext_vector_type(8)));
typedef float f32x4 __attribute__((ext_vector_type(4)));

#define S_LEN 256
#define BATCH 64
#define HID   1024
#define NWG   64
#define SBH   (S_LEN * BATCH * HID)   /* 16777216 */
#define BH    (BATCH * HID)           /* 65536 */

__device__ __forceinline__ float sigm(float v) { return 1.0f / (1.0f + __expf(-v)); }
__device__ __forceinline__ float tanh_fast(float v) {
  float e = __expf(-2.0f * __builtin_fabsf(v));
  float r = (1.0f - e) / (1.0f + e);
  return __builtin_copysignf(r, v);
}

// Convert x, h0, and the 4 weight matrices to bf16 in workspace; zero barrier counters.
__global__ void prep_kernel(const float* __restrict__ x, const float* __restrict__ h0,
                            const float* __restrict__ Wf, const float* __restrict__ Wi,
                            const float* __restrict__ Wg, const float* __restrict__ Wo,
                            __bf16* __restrict__ x_bf, __bf16* __restrict__ w_x,
                            __bf16* __restrict__ w_h, __bf16* __restrict__ h_buf,
                            int* __restrict__ counters) {
  size_t tid = (size_t)blockIdx.x * blockDim.x + threadIdx.x;
  size_t stride = (size_t)gridDim.x * blockDim.x;
  for (size_t i = tid; i < (size_t)SBH; i += stride) x_bf[i] = (__bf16)x[i];
  const float* Ws[4] = {Wf, Wi, Wg, Wo};
  // Each source W is (1024 rows j, 2048 cols): cols 0..1023 -> Wx part, 1024..2047 -> Wh part.
  // Destination row n = g*1024 + j, contiguous k (1024) per row.
  for (size_t i = tid; i < (size_t)4 * 1024 * 2048; i += stride) {
    int g = (int)(i >> 21);
    int j = (int)((i >> 11) & 1023);
    int k = (int)(i & 2047);
    float v = Ws[g][(size_t)j * 2048 + k];
    if (k < HID) w_x[((size_t)(g * 1024 + j)) * HID + k] = (__bf16)v;
    else         w_h[((size_t)(g * 1024 + j)) * HID + (k - HID)] = (__bf16)v;
  }
  for (size_t i = tid; i < (size_t)BH; i += stride) h_buf[i] = (__bf16)h0[i];
  for (size_t i = tid; i < 256; i += stride) counters[i] = 0;
}

// Persistent kernel: 64 WGs x 256 threads. WG w owns hidden units j in [16w, 16w+16);
// wave owns batch tile [16*wave, 16*wave+16). One grid barrier per timestep.
__global__ __launch_bounds__(256, 1) void lstm_kernel(
    const float* __restrict__ x, const float* __restrict__ c0,
    const float* __restrict__ bfp, const float* __restrict__ bip,
    const float* __restrict__ bgp, const float* __restrict__ bop,
    const __bf16* __restrict__ x_bf, const __bf16* __restrict__ w_x,
    const __bf16* __restrict__ w_h, __bf16* __restrict__ h_buf,
    int* __restrict__ counters, float* __restrict__ out) {
  const int tid  = threadIdx.x;
  const int wg   = blockIdx.x;       // 0..63
  const int wave = tid >> 6;         // 0..3  -> batch tile
  const int lane = tid & 63;
  const int quad = lane >> 4;        // 0..3  -> k sub-chunk / row group
  const int l16  = lane & 15;        // A: batch row within tile; B: gate column within WG slice
  const int j    = (wg << 4) + l16;  // hidden unit 0..1023
  const int m_base = wave << 4;

  const float bias0 = bfp[j], bias1 = bip[j], bias2 = bgp[j], bias3 = bop[j];

  // B-fragment row pointers: weight row n = g*1024 + j, + quad*8 k offset.
  const __bf16* pwh0 = w_h + (size_t)j * HID + quad * 8;
  const __bf16* pwh1 = pwh0 + (size_t)1024 * HID;
  const __bf16* pwh2 = pwh1 + (size_t)1024 * HID;
  const __bf16* pwh3 = pwh2 + (size_t)1024 * HID;
  const __bf16* pwx0 = w_x + (size_t)j * HID + quad * 8;
  const __bf16* pwx1 = pwx0 + (size_t)1024 * HID;
  const __bf16* pwx2 = pwx1 + (size_t)1024 * HID;
  const __bf16* pwx3 = pwx2 + (size_t)1024 * HID;

  // Persistent cell state: C/D layout row = quad*4 + r, col = l16.
  int brow[4];
  float c[4];
#pragma unroll
  for (int r = 0; r < 4; ++r) {
    brow[r] = m_base + quad * 4 + r;
    c[r] = c0[(size_t)brow[r] * HID + j];
  }

  for (int t = 0; t < S_LEN; ++t) {
    const __bf16* hp = h_buf + ((t & 1) ? BH : 0) + (size_t)(m_base + l16) * HID + quad * 8;
    __bf16* hn = h_buf + ((t & 1) ? 0 : BH);
    const __bf16* xp = x_bf + ((size_t)(t * BATCH + m_base + l16)) * HID + quad * 8;

    f32x4 acc0 = {0.f, 0.f, 0.f, 0.f};
    f32x4 acc1 = {0.f, 0.f, 0.f, 0.f};
    f32x4 acc2 = {0.f, 0.f, 0.f, 0.f};
    f32x4 acc3 = {0.f, 0.f, 0.f, 0.f};

    // z += h_{t-1} @ Wh^T   (K = 1024 -> 32 chunks of 32)
#pragma unroll 4
    for (int kc = 0; kc < 32; ++kc) {
      bf16x8 a = *(const bf16x8*)(hp + kc * 32);
      acc0 = __builtin_amdgcn_mfma_f32_16x16x32_bf16(a, *(const bf16x8*)(pwh0 + kc * 32), acc0, 0, 0, 0);
      acc1 = __builtin_amdgcn_mfma_f32_16x16x32_bf16(a, *(const bf16x8*)(pwh1 + kc * 32), acc1, 0, 0, 0);
      acc2 = __builtin_amdgcn_mfma_f32_16x16x32_bf16(a, *(const bf16x8*)(pwh2 + kc * 32), acc2, 0, 0, 0);
      acc3 = __builtin_amdgcn_mfma_f32_16x16x32_bf16(a, *(const bf16x8*)(pwh3 + kc * 32), acc3, 0, 0, 0);
    }
    // z += x_t @ Wx^T       (K = 1024 -> 32 chunks of 32)
#pragma unroll 4
    for (int kc = 0; kc < 32; ++kc) {
      bf16x8 a = *(const bf16x8*)(xp + kc * 32);
      acc0 = __builtin_amdgcn_mfma_f32_16x16x32_bf16(a, *(const bf16x8*)(pwx0 + kc * 32), acc0, 0, 0, 0);
      acc1 = __builtin_amdgcn_mfma_f32_16x16x32_bf16(a, *(const bf16x8*)(pwx1 + kc * 32), acc1, 0, 0, 0);
      acc2 = __builtin_amdgcn_mfma_f32_16x16x32_bf16(a, *(const bf16x8*)(pwx2 + kc * 32), acc2, 0, 0, 0);
      acc3 = __builtin_amdgcn_mfma_f32_16x16x32_bf16(a, *(const bf16x8*)(pwx3 + kc * 32), acc3, 0, 0, 0);
    }

    // Gates + cell update, all in-lane (acc layout: row=quad*4+r, col=l16).
#pragma unroll
    for (int r = 0; r < 4; ++r) {
      float fg = sigm(acc0[r] + bias0);
      float ig = sigm(acc1[r] + bias1);
      float gg = tanh_fast(acc2[r] + bias2);
      float og = sigm(acc3[r] + bias3);
      float cn = fg * c[r] + ig * gg;
      c[r] = cn;
      float h = og * tanh_fast(cn);
      size_t oi = (size_t)(t * BATCH + brow[r]) * HID + j;
      out[oi] = x[oi] + h;
      hn[(size_t)brow[r] * HID + j] = (__bf16)h;
      if (t == S_LEN - 1) {
        out[(size_t)SBH + (size_t)brow[r] * HID + j] = h;            // h_f
        out[(size_t)SBH + BH + (size_t)brow[r] * HID + j] = cn;      // c_f
      }
    }

    // Grid barrier for step t (counters pre-zeroed; no reuse -> no wraparound).
    __syncthreads();   // drains this WG's global writes (vmcnt(0) before s_barrier)
    if (tid == 0) {
      __threadfence(); // L2 writeback so remote XCDs can see our h writes
      __hip_atomic_fetch_add(counters + t, 1, __ATOMIC_RELEASE, __HIP_MEMORY_SCOPE_AGENT);
      while (__hip_atomic_load(counters + t, __ATOMIC_ACQUIRE, __HIP_MEMORY_SCOPE_AGENT) < NWG) {
        __builtin_amdgcn_s_sleep(1);
      }
    }
    __syncthreads();
  }
}

extern "C" void kernel_launch(void* const* d_in, const int* in_sizes, int n_in,
                              void* d_out, int out_size, void* d_ws, size_t ws_size,
                              hipStream_t stream) {
  const float* x   = (const float*)d_in[0];
  const float* h0  = (const float*)d_in[1];
  const float* c0  = (const float*)d_in[2];
  const float* Wf  = (const float*)d_in[3];
  const float* bf_ = (const float*)d_in[4];
  const float* Wi  = (const float*)d_in[5];
  const float* bi_ = (const float*)d_in[6];
  const float* Wg  = (const float*)d_in[7];
  const float* bg_ = (const float*)d_in[8];
  const float* Wo  = (const float*)d_in[9];
  const float* bo_ = (const float*)d_in[10];

  char* ws = (char*)d_ws;
  size_t off = 0;
  __bf16* x_bf = (__bf16*)(ws + off); off += (size_t)SBH * 2;              // 32 MB
  __bf16* w_x  = (__bf16*)(ws + off); off += (size_t)4 * 1024 * 1024 * 2;  // 8 MB
  __bf16* w_h  = (__bf16*)(ws + off); off += (size_t)4 * 1024 * 1024 * 2;  // 8 MB
  __bf16* h_buf = (__bf16*)(ws + off); off += (size_t)2 * BH * 2;          // 256 KB
  int* counters = (int*)(ws + off); off += 256 * sizeof(int);
  if (ws_size < off) return;  // deterministic per-session; avoids corruption if ws too small

  float* out = (float*)d_out;

  prep_kernel<<<2048, 256, 0, stream>>>(x, h0, Wf, Wi, Wg, Wo, x_bf, w_x, w_h, h_buf, counters);
  lstm_kernel<<<NWG, 256, 0, stream>>>(x, c0, bf_, bi_, bg_, bo_, x_bf, w_x, w_h, h_buf, counters, out);
}

// Round 2
// 2651.106 us; speedup vs baseline: 4.3027x; 4.3027x over previous
//
#include <hip/hip_runtime.h>

typedef __bf16 bf16x8 __attribute__((ext_vector_type(8)));
typedef float f32x4 __attribute__((ext_vector_type(4)));
typedef unsigned int u32x4 __attribute__((ext_vector_type(4)));

#define S_LEN 256
#define BATCH 64
#define HID   1024
#define NWG   256
#define SBH   (S_LEN * BATCH * HID)   /* 16777216 */
#define BH    (BATCH * HID)           /* 65536 */

__device__ __forceinline__ float sigm(float v) { return 1.0f / (1.0f + __expf(-v)); }
__device__ __forceinline__ float tanh_fast(float v) {
  float e = __expf(-2.0f * __builtin_fabsf(v));
  float r = (1.0f - e) / (1.0f + e);
  return __builtin_copysignf(r, v);
}

// Convert x and the 4 weight matrices to bf16 in workspace; init h_buf; zero counters.
__global__ void prep_kernel(const float* __restrict__ x, const float* __restrict__ h0,
                            const float* __restrict__ Wf, const float* __restrict__ Wi,
                            const float* __restrict__ Wg, const float* __restrict__ Wo,
                            __bf16* __restrict__ x_bf, __bf16* __restrict__ w_x,
                            __bf16* __restrict__ w_h, __bf16* __restrict__ h_buf,
                            int* __restrict__ counters) {
  size_t tid = (size_t)blockIdx.x * blockDim.x + threadIdx.x;
  size_t stride = (size_t)gridDim.x * blockDim.x;
  for (size_t i = tid; i < (size_t)SBH; i += stride) x_bf[i] = (__bf16)x[i];
  const float* Ws[4] = {Wf, Wi, Wg, Wo};
  // Source W_g is (1024 rows j, 2048 cols c): c<1024 -> Wx, c>=1024 -> Wh.
  for (size_t i = tid; i < (size_t)4 * 1024 * 2048; i += stride) {
    int g = (int)(i >> 21);
    int j = (int)((i >> 11) & 1023);
    int k = (int)(i & 2047);
    float v = Ws[g][(size_t)j * 2048 + k];
    if (k < HID) w_x[((size_t)(g * 1024 + j)) * HID + k] = (__bf16)v;
    else         w_h[((size_t)(g * 1024 + j)) * HID + (k - HID)] = (__bf16)v;
  }
  for (size_t i = tid; i < (size_t)BH; i += stride) h_buf[i] = (__bf16)h0[i];
  for (size_t i = tid; i < 256; i += stride) counters[i] = 0;
}

// 256 WGs x 256 threads, 1 WG/CU. WG (m,ug): batches [16m,16m+16), units [16ug,16ug+16).
// Wave g computes gate g's 16x16 z-tile with B resident in 256 VGPRs (K=2048: h then x).
// A (h||x for this WG's 16 batches) staged per step into LDS in MFMA-frag-major layout.
// h communicated cross-XCD via sc0/sc1 (coherence-point) loads + agent atomic stores;
// grid barrier = relaxed fetch_add + relaxed spin (NO acquire/release fences -> no L2 inv).
__global__ __launch_bounds__(256, 1) void lstm_kernel(
    const float* __restrict__ x, const float* __restrict__ c0,
    const float* __restrict__ bfp, const float* __restrict__ bip,
    const float* __restrict__ bgp, const float* __restrict__ bop,
    const __bf16* __restrict__ x_bf, const __bf16* __restrict__ w_x,
    const __bf16* __restrict__ w_h, __bf16* __restrict__ h_buf,
    int* __restrict__ counters, float* __restrict__ out) {
  const int tid    = threadIdx.x;
  const int wgid   = blockIdx.x;
  const int m_base = (wgid >> 6) << 4;   // batch tile base: 0/16/32/48
  const int U      = (wgid & 63) << 4;   // hidden-unit base (same-ug WGs land on same XCD)
  const int wave   = tid >> 6;           // gate index 0..3 (f,i,g,o)
  const int lane   = tid & 63;
  const int l16    = lane & 15;
  const int kq     = (lane >> 4) * 8;    // k sub-offset within a 32-chunk

  __shared__ __align__(16) __bf16 Afrag[64 * 64 * 8];  // 64 kc x 64 lanes x 16B = 64 KB
  __shared__ float zbuf[4][16][17];                    // gate-transpose buffer (padded)

  // ---- Load resident B fragments (once): wave's gate, 16 unit-cols, K=2048 ----
  bf16x8 B[64];
  {
    const int j = U + l16;  // B col = unit
    const __bf16* bh = w_h + ((size_t)(wave * 1024 + j)) * HID + kq;
    const __bf16* bx = w_x + ((size_t)(wave * 1024 + j)) * HID + kq;
#pragma unroll
    for (int kc = 0; kc < 32; ++kc) B[kc]      = *(const bf16x8*)(bh + kc * 32);
#pragma unroll
    for (int kc = 0; kc < 32; ++kc) B[32 + kc] = *(const bf16x8*)(bx + kc * 32);
  }

  // ---- Per-thread cell state: thread = (batch-local b_loc, unit-local u_loc) ----
  const int b_loc  = tid >> 4;
  const int u_loc  = tid & 15;
  const int j_t    = U + u_loc;
  const int b_glob = m_base + b_loc;
  float c = c0[(size_t)b_glob * HID + j_t];
  const float bias_f = bfp[j_t], bias_i = bip[j_t], bias_g = bgp[j_t], bias_o = bop[j_t];

  for (int t = 0; t < S_LEN; ++t) {
    const size_t roff = (t & 1) ? (size_t)BH : 0;  // read  buffer (t=0 reads h0 in buf0)
    const size_t woff = (t & 1) ? 0 : (size_t)BH;  // write buffer

    // ---- Stage A into LDS, frag-major: frag f=(kc,l) at byte offset f*16 ----
    {
      u32x4 hv[8];
#pragma unroll
      for (int i = 0; i < 8; ++i) {      // kc 0..31 : h part (coherence-point loads)
        int f = i * 256 + tid;
        int kc = f >> 6, l = f & 63;
        int row = l & 15, k = kc * 32 + (l >> 4) * 8;
        unsigned long ga = (unsigned long)(h_buf + roff + (size_t)(m_base + row) * HID + k);
        asm volatile("global_load_dwordx4 %0, %1, off sc0 sc1" : "=v"(hv[i]) : "v"(ga));
      }
      asm volatile("s_waitcnt vmcnt(0)" ::: "memory");
#pragma unroll
      for (int i = 0; i < 8; ++i) {
        int f = i * 256 + tid;
        *(u32x4*)(&Afrag[(size_t)f * 8]) = hv[i];
      }
#pragma unroll
      for (int i = 8; i < 16; ++i) {     // kc 32..63 : x part (normal cached loads)
        int f = i * 256 + tid;
        int kc = f >> 6, l = f & 63;
        int row = l & 15, k = kc * 32 + (l >> 4) * 8 - 1024;
        const bf16x8* ga = (const bf16x8*)(x_bf + ((size_t)(t * BATCH + m_base + row)) * HID + k);
        *(bf16x8*)(&Afrag[(size_t)f * 8]) = *ga;
      }
    }
    __syncthreads();

    // ---- K-loop: 64 MFMAs, A from LDS, B from registers (2 chains for ILP) ----
    f32x4 acc0 = {0.f, 0.f, 0.f, 0.f};
    f32x4 acc1 = {0.f, 0.f, 0.f, 0.f};
#pragma unroll
    for (int kc = 0; kc < 32; ++kc) {
      bf16x8 a = *(const bf16x8*)(&Afrag[((size_t)kc * 64 + lane) * 8]);
      acc0 = __builtin_amdgcn_mfma_f32_16x16x32_bf16(a, B[kc], acc0, 0, 0, 0);
    }
#pragma unroll
    for (int kc = 32; kc < 64; ++kc) {
      bf16x8 a = *(const bf16x8*)(&Afrag[((size_t)kc * 64 + lane) * 8]);
      acc1 = __builtin_amdgcn_mfma_f32_16x16x32_bf16(a, B[kc], acc1, 0, 0, 0);
    }
    // z tile -> LDS: C/D layout row = quad*4+r (batch-local), col = l16 (unit-local)
    {
      int q = lane >> 4;
#pragma unroll
      for (int r = 0; r < 4; ++r) zbuf[wave][q * 4 + r][l16] = acc0[r] + acc1[r];
    }
    __syncthreads();

    // ---- Per-thread gate combine + cell update ----
    {
      float fg = sigm(zbuf[0][b_loc][u_loc] + bias_f);
      float ig = sigm(zbuf[1][b_loc][u_loc] + bias_i);
      float gg = tanh_fast(zbuf[2][b_loc][u_loc] + bias_g);
      float og = sigm(zbuf[3][b_loc][u_loc] + bias_o);
      c = fg * c + ig * gg;
      float h = og * tanh_fast(c);
      size_t oi = ((size_t)(t * BATCH + b_glob)) * HID + j_t;
      out[oi] = x[oi] + h;
      __bf16 hb16 = (__bf16)h;
      unsigned short hbits = __builtin_bit_cast(unsigned short, hb16);
      __hip_atomic_store((unsigned short*)(h_buf + woff + (size_t)b_glob * HID + j_t),
                         hbits, __ATOMIC_RELAXED, __HIP_MEMORY_SCOPE_AGENT);
      if (t == S_LEN - 1) {
        out[(size_t)SBH + (size_t)b_glob * HID + j_t] = h;        // h_f
        out[(size_t)SBH + BH + (size_t)b_glob * HID + j_t] = c;   // c_f
      }
    }

    // ---- Grid barrier: relaxed add + relaxed spin (no cache-inv storm) ----
    __syncthreads();  // drains vmcnt(0): h stores reached the coherence point
    if (tid == 0) {
      __hip_atomic_fetch_add(counters + t, 1, __ATOMIC_RELAXED, __HIP_MEMORY_SCOPE_AGENT);
      while (__hip_atomic_load(counters + t, __ATOMIC_RELAXED, __HIP_MEMORY_SCOPE_AGENT) < NWG) {
        __builtin_amdgcn_s_sleep(4);
      }
    }
    __syncthreads();
  }
}

extern "C" void kernel_launch(void* const* d_in, const int* in_sizes, int n_in,
                              void* d_out, int out_size, void* d_ws, size_t ws_size,
                              hipStream_t stream) {
  const float* x   = (const float*)d_in[0];
  const float* h0  = (const float*)d_in[1];
  const float* c0  = (const float*)d_in[2];
  const float* Wf  = (const float*)d_in[3];
  const float* bf_ = (const float*)d_in[4];
  const float* Wi  = (const float*)d_in[5];
  const float* bi_ = (const float*)d_in[6];
  const float* Wg  = (const float*)d_in[7];
  const float* bg_ = (const float*)d_in[8];
  const float* Wo  = (const float*)d_in[9];
  const float* bo_ = (const float*)d_in[10];

  char* ws = (char*)d_ws;
  size_t off = 0;
  __bf16* x_bf = (__bf16*)(ws + off); off += (size_t)SBH * 2;              // 32 MB
  __bf16* w_x  = (__bf16*)(ws + off); off += (size_t)4 * 1024 * 1024 * 2;  // 8 MB
  __bf16* w_h  = (__bf16*)(ws + off); off += (size_t)4 * 1024 * 1024 * 2;  // 8 MB
  __bf16* h_buf = (__bf16*)(ws + off); off += (size_t)2 * BH * 2;          // 256 KB
  int* counters = (int*)(ws + off); off += 256 * sizeof(int);
  if (ws_size < off) return;

  float* out = (float*)d_out;

  prep_kernel<<<2048, 256, 0, stream>>>(x, h0, Wf, Wi, Wg, Wo, x_bf, w_x, w_h, h_buf, counters);
  lstm_kernel<<<NWG, 256, 0, stream>>>(x, c0, bf_, bi_, bg_, bo_, x_bf, w_x, w_h, h_buf, counters, out);
}